// Round 8
// baseline (645.437 us; speedup 1.0000x reference)
//
#include <hip/hip_runtime.h>
#include <hip/hip_fp16.h>

#define DIM 64
#define BN_EPS 1e-5f
#define RSHIFT 8          // 256 nodes per range
#define RSIZE 256
#define EPB 8192          // edges per k_bin block

// ---------------- degree: deg[dst[e]] += 1 (int4 edge reads) ----------------
__global__ void k_degree(const int* __restrict__ dst, int* __restrict__ deg, int E) {
    int e = blockIdx.x * blockDim.x + threadIdx.x;
    int E4 = E >> 2;
    if (e < E4) {
        int4 v = ((const int4*)dst)[e];
        atomicAdd(&deg[v.x], 1);
        atomicAdd(&deg[v.y], 1);
        atomicAdd(&deg[v.z], 1);
        atomicAdd(&deg[v.w], 1);
    }
    if (e < (E & 3)) atomicAdd(&deg[dst[(E4 << 2) + e]], 1);
}

// ---------------- prep: dinv + per-range edge counts + zero stats ----------------
// block b covers nodes [b*256, b*256+256) == range b exactly
__global__ __launch_bounds__(256) void k_prep(const int* __restrict__ deg,
                                              float* __restrict__ dinv,
                                              int* __restrict__ rangecnt,
                                              float* __restrict__ gstats, int N) {
    if (blockIdx.x == 0 && threadIdx.x < 128) gstats[threadIdx.x] = 0.f;
    __shared__ int sred[256];
    int i = blockIdx.x * 256 + threadIdx.x;
    int v = (i < N) ? deg[i] : 0;
    if (i < N) dinv[i] = rsqrtf((float)v + 1.0f);  // +1 self-loop
    sred[threadIdx.x] = v;
    __syncthreads();
    for (int o = 128; o > 0; o >>= 1) {
        if (threadIdx.x < o) sred[threadIdx.x] += sred[threadIdx.x + o];
        __syncthreads();
    }
    if (threadIdx.x == 0) rangecnt[blockIdx.x] = sred[0];
}

// ---------------- rangescan: exclusive scan of rangecnt (P <= 512), init cursor ----------------
__global__ void k_rangescan(const int* __restrict__ rangecnt, int* __restrict__ gbase,
                            int* __restrict__ gcursor, int P, int E) {
    __shared__ int s[512];
    int v = ((int)threadIdx.x < P) ? rangecnt[threadIdx.x] : 0;
    s[threadIdx.x] = v;
    __syncthreads();
    for (int off = 1; off < 512; off <<= 1) {
        int t = (threadIdx.x >= (unsigned)off) ? s[threadIdx.x - off] : 0;
        __syncthreads();
        s[threadIdx.x] += t;
        __syncthreads();
    }
    if ((int)threadIdx.x < P) {
        int ex = s[threadIdx.x] - v;
        gbase[threadIdx.x] = ex;
        gcursor[threadIdx.x] = ex;
    }
    if ((int)threadIdx.x == P - 1) gbase[P] = s[threadIdx.x];  // = E
}

// ---------------- bin: group edges by dst-range, block-exclusive coalesced runs ----------------
// pk[pos] = (dstlocal << 20) | src   (src < 2^20, dstlocal < 256)
__global__ __launch_bounds__(256) void k_bin(const int* __restrict__ src,
                                             const int* __restrict__ dst,
                                             int* __restrict__ gcursor,
                                             int* __restrict__ pk, int P, int E) {
    __shared__ int hist[512], gofs[512], lcnt[512];
    for (int b = threadIdx.x; b < P; b += 256) { hist[b] = 0; lcnt[b] = 0; }
    __syncthreads();
    const int base4 = blockIdx.x * (EPB / 4);
    // phase 1: histogram
    for (int i = 0; i < EPB / 4 / 256; ++i) {
        int idx = base4 + i * 256 + threadIdx.x;
        int e0 = idx << 2;
        if (e0 + 3 < E) {
            int4 d4 = ((const int4*)dst)[idx];
            atomicAdd(&hist[d4.x >> RSHIFT], 1);
            atomicAdd(&hist[d4.y >> RSHIFT], 1);
            atomicAdd(&hist[d4.z >> RSHIFT], 1);
            atomicAdd(&hist[d4.w >> RSHIFT], 1);
        } else {
            for (int k = 0; k < 4; ++k)
                if (e0 + k < E) atomicAdd(&hist[dst[e0 + k] >> RSHIFT], 1);
        }
    }
    __syncthreads();
    // phase 2: reserve global spans (one atomic per non-empty bucket per block)
    for (int b = threadIdx.x; b < P; b += 256)
        if (hist[b] > 0) gofs[b] = atomicAdd(&gcursor[b], hist[b]);
    __syncthreads();
    // phase 3: place into reserved spans
    for (int i = 0; i < EPB / 4 / 256; ++i) {
        int idx = base4 + i * 256 + threadIdx.x;
        int e0 = idx << 2;
        if (e0 + 3 < E) {
            int4 d4 = ((const int4*)dst)[idx];
            int4 s4 = ((const int4*)src)[idx];
            int b, p;
            b = d4.x >> RSHIFT; p = ((d4.x & (RSIZE - 1)) << 20) | s4.x;
            pk[gofs[b] + atomicAdd(&lcnt[b], 1)] = p;
            b = d4.y >> RSHIFT; p = ((d4.y & (RSIZE - 1)) << 20) | s4.y;
            pk[gofs[b] + atomicAdd(&lcnt[b], 1)] = p;
            b = d4.z >> RSHIFT; p = ((d4.z & (RSIZE - 1)) << 20) | s4.z;
            pk[gofs[b] + atomicAdd(&lcnt[b], 1)] = p;
            b = d4.w >> RSHIFT; p = ((d4.w & (RSIZE - 1)) << 20) | s4.w;
            pk[gofs[b] + atomicAdd(&lcnt[b], 1)] = p;
        } else {
            for (int k = 0; k < 4; ++k) {
                if (e0 + k < E) {
                    int d = dst[e0 + k];
                    int b = d >> RSHIFT;
                    int p = ((d & (RSIZE - 1)) << 20) | src[e0 + k];
                    pk[gofs[b] + atomicAdd(&lcnt[b], 1)] = p;
                }
            }
        }
    }
}

// ---------------- h2 = fp16( (x @ W) * dinv[row] ) : row per thread ----------------
__global__ __launch_bounds__(256) void k_gemm(const float* __restrict__ x,
                                              const float* __restrict__ W,
                                              const float* __restrict__ dinv,
                                              __half* __restrict__ h2, int N) {
    __shared__ float Wl[DIM * DIM];
    for (int i = threadIdx.x; i < DIM * DIM; i += 256) Wl[i] = W[i];
    __syncthreads();
    int r = blockIdx.x * 256 + threadIdx.x;
    if (r >= N) return;
    const float4* xr4 = (const float4*)(x + (size_t)r * DIM);
    float4 acc[16];
#pragma unroll
    for (int j = 0; j < 16; ++j) acc[j] = make_float4(0.f, 0.f, 0.f, 0.f);
    for (int k0 = 0; k0 < 16; ++k0) {
        float4 xv = xr4[k0];
#pragma unroll
        for (int kk = 0; kk < 4; ++kk) {
            float xs = (&xv.x)[kk];
            const float4* wrow = (const float4*)(Wl + (k0 * 4 + kk) * DIM);
#pragma unroll
            for (int j = 0; j < 16; ++j) {
                float4 w = wrow[j];
                acc[j].x += xs * w.x;
                acc[j].y += xs * w.y;
                acc[j].z += xs * w.z;
                acc[j].w += xs * w.w;
            }
        }
    }
    float dr = dinv[r];
    float4* hr4 = (float4*)(h2 + (size_t)r * DIM);
    union { __half2 h[4]; float4 f4; } pack;
#pragma unroll
    for (int j = 0; j < 16; j += 2) {
        pack.h[0] = __float22half2_rn(make_float2(acc[j].x * dr, acc[j].y * dr));
        pack.h[1] = __float22half2_rn(make_float2(acc[j].z * dr, acc[j].w * dr));
        pack.h[2] = __float22half2_rn(make_float2(acc[j + 1].x * dr, acc[j + 1].y * dr));
        pack.h[3] = __float22half2_rn(make_float2(acc[j + 1].z * dr, acc[j + 1].w * dr));
        hr4[j >> 1] = pack.f4;
    }
}

// ---------------- range aggregate: LDS fp32 accumulator, fused epilogue ----------------
// block = range r (256 nodes). Edges pre-grouped (unsorted within range).
__global__ __launch_bounds__(256) void k_rangeagg(
        const int* __restrict__ pk, const int* __restrict__ gbase,
        const __half* __restrict__ h2, const float* __restrict__ dinv,
        const float* __restrict__ b, float* __restrict__ out,
        float* __restrict__ gsum, float* __restrict__ gsumsq, int N) {
    __shared__ float acc[RSIZE * DIM];   // 64 KB
    __shared__ float s1[256], s2[256];
    const int lane = threadIdx.x & 63;
    const int wave = threadIdx.x >> 6;
    const int r = blockIdx.x;
    for (int i = threadIdx.x; i < RSIZE * DIM; i += 256) acc[i] = 0.f;
    __syncthreads();
    const int ebeg = gbase[r], eend = gbase[r + 1];
    const __half* hb = h2 + lane;
    for (int cbase = ebeg + (wave << 6); cbase < eend; cbase += 4 * 64) {
        const int nval = min(64, eend - cbase);
        int pv = pk[cbase + min(lane, nval - 1)];
        if (nval == 64) {
#pragma unroll
            for (int g = 0; g < 64; g += 8) {
                int pA[8];
                float vA[8];
#pragma unroll
                for (int k = 0; k < 8; ++k) pA[k] = __builtin_amdgcn_readlane(pv, g + k);
#pragma unroll
                for (int k = 0; k < 8; ++k)
                    vA[k] = __half2float(hb[(size_t)(pA[k] & 0xFFFFF) * DIM]);
#pragma unroll
                for (int k = 0; k < 8; ++k)
                    atomicAdd(&acc[(pA[k] >> 20) * DIM + lane], vA[k]);
            }
        } else {
            for (int j = 0; j < nval; ++j) {
                int p = __builtin_amdgcn_readlane(pv, j);
                float v = __half2float(hb[(size_t)(p & 0xFFFFF) * DIM]);
                atomicAdd(&acc[(p >> 20) * DIM + lane], v);
            }
        }
    }
    __syncthreads();
    // epilogue: self-term + bias + relu + stats, coalesced writeout
    const float bf = b[lane];
    float lsum = 0.f, lsq = 0.f;
    const int d0 = r << RSHIFT;
    for (int dl = wave; dl < RSIZE; dl += 4) {
        int d = d0 + dl;
        if (d < N) {
            size_t di = (size_t)d * DIM + lane;
            float a = (acc[dl * DIM + lane] + __half2float(h2[di])) * dinv[d] + bf;
            a = fmaxf(a, 0.f);
            out[di] = a;
            lsum += a;
            lsq += a * a;
        }
    }
    s1[threadIdx.x] = lsum;
    s2[threadIdx.x] = lsq;
    __syncthreads();
    if (threadIdx.x < 64) {
        float t1 = s1[threadIdx.x] + s1[threadIdx.x + 64] + s1[threadIdx.x + 128] + s1[threadIdx.x + 192];
        float t2 = s2[threadIdx.x] + s2[threadIdx.x + 64] + s2[threadIdx.x + 128] + s2[threadIdx.x + 192];
        atomicAdd(&gsum[threadIdx.x], t1);
        atomicAdd(&gsumsq[threadIdx.x], t2);
    }
}

// ---------------- bn2 (stats fused): out = a*scale + shift, float4, in-place ----------------
__global__ void k_bn2(float4* __restrict__ a, const float* __restrict__ gsum,
                      const float* __restrict__ gsumsq, const float* __restrict__ gamma,
                      const float* __restrict__ beta, int N, int total4) {
    __shared__ float sc[DIM], sh[DIM];
    if (threadIdx.x < DIM) {
        float inv_n = 1.0f / (float)N;
        float mean = gsum[threadIdx.x] * inv_n;
        float var = gsumsq[threadIdx.x] * inv_n - mean * mean;
        float istd = rsqrtf(var + BN_EPS);
        float s = gamma[threadIdx.x] * istd;
        sc[threadIdx.x] = s;
        sh[threadIdx.x] = beta[threadIdx.x] - mean * s;
    }
    __syncthreads();
    int i = blockIdx.x * blockDim.x + threadIdx.x;
    int stride = gridDim.x * blockDim.x;  // 2048*256 = 524288 ≡ 0 (mod 16)
    int f4 = i & 15;
    float4 scv = ((const float4*)sc)[f4];
    float4 shv = ((const float4*)sh)[f4];
    for (; i < total4; i += stride) {
        float4 v = a[i];
        v.x = v.x * scv.x + shv.x;
        v.y = v.y * scv.y + shv.y;
        v.z = v.z * scv.z + shv.z;
        v.w = v.w * scv.w + shv.w;
        a[i] = v;
    }
}

extern "C" void kernel_launch(void* const* d_in, const int* in_sizes, int n_in,
                              void* d_out, int out_size, void* d_ws, size_t ws_size,
                              hipStream_t stream) {
    const float* x     = (const float*)d_in[0];
    const int*   ei    = (const int*)d_in[1];
    const float* W     = (const float*)d_in[2];
    const float* b     = (const float*)d_in[3];
    const float* gamma = (const float*)d_in[4];
    const float* beta  = (const float*)d_in[5];
    float* out = (float*)d_out;

    const int N = in_sizes[0] / DIM;  // 100000
    const int E = in_sizes[1] / 2;    // 1000000
    const int* esrc = ei;
    const int* edst = ei + E;
    const int P = (N + RSIZE - 1) >> RSHIFT;   // 391 ranges (must be <= 512)
    const int nbin = (E + EPB - 1) / EPB;      // 123 bin blocks

    // workspace layout
    char* ws = (char*)d_ws;
    size_t off = 0;
    int* deg = (int*)(ws + off);        off += (size_t)N * sizeof(int);
    off = (off + 255) & ~(size_t)255;
    float* dinv = (float*)(ws + off);   off += (size_t)N * sizeof(float);
    off = (off + 255) & ~(size_t)255;
    int* rangecnt = (int*)(ws + off);   off += 512 * sizeof(int);
    int* gbase = (int*)(ws + off);      off += 520 * sizeof(int);
    int* gcursor = (int*)(ws + off);    off += 512 * sizeof(int);
    float* gsum = (float*)(ws + off);   off += 64 * sizeof(float);
    float* gsumsq = (float*)(ws + off); off += 64 * sizeof(float);
    off = (off + 255) & ~(size_t)255;
    int* pk = (int*)(ws + off);         off += (size_t)E * sizeof(int);
    off = (off + 255) & ~(size_t)255;
    __half* h2 = (__half*)(ws + off);   off += (size_t)N * DIM * sizeof(__half);

    hipMemsetAsync(deg, 0, (size_t)N * sizeof(int), stream);

    k_degree<<<((E >> 2) + 255) / 256, 256, 0, stream>>>(edst, deg, E);
    k_prep<<<P, 256, 0, stream>>>(deg, dinv, rangecnt, gsum, N);
    k_rangescan<<<1, 512, 0, stream>>>(rangecnt, gbase, gcursor, P, E);
    k_bin<<<nbin, 256, 0, stream>>>(esrc, edst, gcursor, pk, P, E);
    k_gemm<<<P, 256, 0, stream>>>(x, W, dinv, h2, N);
    k_rangeagg<<<P, 256, 0, stream>>>(pk, gbase, h2, dinv, b, out, gsum, gsumsq, N);
    k_bn2<<<2048, 256, 0, stream>>>((float4*)out, gsum, gsumsq, gamma, beta, N, N * DIM / 4);
}

// Round 9
// 274.786 us; speedup vs baseline: 2.3489x; 2.3489x over previous
//
#include <hip/hip_runtime.h>
#include <hip/hip_fp16.h>

#define DIM 64
#define BN_EPS 1e-5f
#define RSHIFT 8          // 256 nodes per range
#define RSIZE 256
#define EPB 8192          // edges per k_bin block

// ---------------- degree: deg[dst[e]] += 1 (int4 edge reads) ----------------
__global__ void k_degree(const int* __restrict__ dst, int* __restrict__ deg, int E) {
    int e = blockIdx.x * blockDim.x + threadIdx.x;
    int E4 = E >> 2;
    if (e < E4) {
        int4 v = ((const int4*)dst)[e];
        atomicAdd(&deg[v.x], 1);
        atomicAdd(&deg[v.y], 1);
        atomicAdd(&deg[v.z], 1);
        atomicAdd(&deg[v.w], 1);
    }
    if (e < (E & 3)) atomicAdd(&deg[dst[(E4 << 2) + e]], 1);
}

// ---------------- prep: dinv + per-range edge counts + zero stats ----------------
__global__ __launch_bounds__(256) void k_prep(const int* __restrict__ deg,
                                              float* __restrict__ dinv,
                                              int* __restrict__ rangecnt,
                                              float* __restrict__ gstats, int N) {
    if (blockIdx.x == 0 && threadIdx.x < 128) gstats[threadIdx.x] = 0.f;
    __shared__ int sred[256];
    int i = blockIdx.x * 256 + threadIdx.x;
    int v = (i < N) ? deg[i] : 0;
    if (i < N) dinv[i] = rsqrtf((float)v + 1.0f);  // +1 self-loop
    sred[threadIdx.x] = v;
    __syncthreads();
    for (int o = 128; o > 0; o >>= 1) {
        if (threadIdx.x < o) sred[threadIdx.x] += sred[threadIdx.x + o];
        __syncthreads();
    }
    if (threadIdx.x == 0) rangecnt[blockIdx.x] = sred[0];
}

// ---------------- rangescan: exclusive scan of rangecnt (P <= 512) ----------------
__global__ void k_rangescan(const int* __restrict__ rangecnt, int* __restrict__ gbase,
                            int* __restrict__ gcursor, int* __restrict__ rowptr,
                            int P, int N, int E) {
    __shared__ int s[512];
    int v = ((int)threadIdx.x < P) ? rangecnt[threadIdx.x] : 0;
    s[threadIdx.x] = v;
    __syncthreads();
    for (int off = 1; off < 512; off <<= 1) {
        int t = (threadIdx.x >= (unsigned)off) ? s[threadIdx.x - off] : 0;
        __syncthreads();
        s[threadIdx.x] += t;
        __syncthreads();
    }
    if ((int)threadIdx.x < P) {
        int ex = s[threadIdx.x] - v;
        gbase[threadIdx.x] = ex;
        gcursor[threadIdx.x] = ex;
    }
    if ((int)threadIdx.x == P - 1) gbase[P] = s[threadIdx.x];  // = E
    if (threadIdx.x == 0) rowptr[N] = E;
}

// ---------------- bin: group edges by dst-range into block-exclusive runs ----------------
// pk[pos] = (dstlocal << 20) | src   (src < 2^20, dstlocal < 256)
__global__ __launch_bounds__(256) void k_bin(const int* __restrict__ src,
                                             const int* __restrict__ dst,
                                             int* __restrict__ gcursor,
                                             int* __restrict__ pk, int P, int E) {
    __shared__ int hist[512], gofs[512], lcnt[512];
    for (int b = threadIdx.x; b < P; b += 256) { hist[b] = 0; lcnt[b] = 0; }
    __syncthreads();
    const int base4 = blockIdx.x * (EPB / 4);
    for (int i = 0; i < EPB / 4 / 256; ++i) {
        int idx = base4 + i * 256 + threadIdx.x;
        int e0 = idx << 2;
        if (e0 + 3 < E) {
            int4 d4 = ((const int4*)dst)[idx];
            atomicAdd(&hist[d4.x >> RSHIFT], 1);
            atomicAdd(&hist[d4.y >> RSHIFT], 1);
            atomicAdd(&hist[d4.z >> RSHIFT], 1);
            atomicAdd(&hist[d4.w >> RSHIFT], 1);
        } else {
            for (int k = 0; k < 4; ++k)
                if (e0 + k < E) atomicAdd(&hist[dst[e0 + k] >> RSHIFT], 1);
        }
    }
    __syncthreads();
    for (int b = threadIdx.x; b < P; b += 256)
        if (hist[b] > 0) gofs[b] = atomicAdd(&gcursor[b], hist[b]);
    __syncthreads();
    for (int i = 0; i < EPB / 4 / 256; ++i) {
        int idx = base4 + i * 256 + threadIdx.x;
        int e0 = idx << 2;
        if (e0 + 3 < E) {
            int4 d4 = ((const int4*)dst)[idx];
            int4 s4 = ((const int4*)src)[idx];
            int b;
            b = d4.x >> RSHIFT; pk[gofs[b] + atomicAdd(&lcnt[b], 1)] = ((d4.x & (RSIZE - 1)) << 20) | s4.x;
            b = d4.y >> RSHIFT; pk[gofs[b] + atomicAdd(&lcnt[b], 1)] = ((d4.y & (RSIZE - 1)) << 20) | s4.y;
            b = d4.z >> RSHIFT; pk[gofs[b] + atomicAdd(&lcnt[b], 1)] = ((d4.z & (RSIZE - 1)) << 20) | s4.z;
            b = d4.w >> RSHIFT; pk[gofs[b] + atomicAdd(&lcnt[b], 1)] = ((d4.w & (RSIZE - 1)) << 20) | s4.w;
        } else {
            for (int k = 0; k < 4; ++k) {
                if (e0 + k < E) {
                    int d = dst[e0 + k];
                    int b = d >> RSHIFT;
                    pk[gofs[b] + atomicAdd(&lcnt[b], 1)] = ((d & (RSIZE - 1)) << 20) | src[e0 + k];
                }
            }
        }
    }
}

// ---------------- sortrange: per-range LDS counting sort + rowptr + chunkstart ----------------
// block r: local exclusive scan of deg over the range's 256 nodes, then scatter
// src into dst-sorted order within the range's contiguous window (L2-local).
__global__ __launch_bounds__(256) void k_sortrange(
        const int* __restrict__ deg, const int* __restrict__ gbase,
        const int* __restrict__ pk, int* __restrict__ ssrc,
        int* __restrict__ rowptr, int* __restrict__ chunkstart, int N) {
    __shared__ int ls[256], lcur[256];
    const int r = blockIdx.x;
    const int d0 = r << RSHIFT;
    const int i = d0 + threadIdx.x;
    const int ebeg = gbase[r], eend = gbase[r + 1];
    int dg = (i < N) ? deg[i] : 0;
    ls[threadIdx.x] = dg;
    __syncthreads();
    for (int off = 1; off < 256; off <<= 1) {
        int t = (threadIdx.x >= (unsigned)off) ? ls[threadIdx.x - off] : 0;
        __syncthreads();
        ls[threadIdx.x] += t;
        __syncthreads();
    }
    int lofs = ls[threadIdx.x] - dg;  // local exclusive
    lcur[threadIdx.x] = lofs;
    if (i < N) {
        int rs = ebeg + lofs;
        rowptr[i] = rs;
        int rn = rs + dg;
        int c0 = (rs + 63) >> 6;
        int c1 = (rn + 63) >> 6;
        for (int c = c0; c < c1; ++c) chunkstart[c] = i;
    }
    __syncthreads();
    for (int j = ebeg + threadIdx.x; j < eend; j += 256) {
        int p = pk[j];
        int dl = p >> 20;
        ssrc[ebeg + atomicAdd(&lcur[dl], 1)] = p & 0xFFFFF;
    }
}

// ---------------- h2 = fp16(h*dinv) AND seed out with fp32 self term ----------------
__global__ __launch_bounds__(256) void k_gemm(const float* __restrict__ x,
                                              const float* __restrict__ W,
                                              const float* __restrict__ dinv,
                                              __half* __restrict__ h2,
                                              float* __restrict__ outseed, int N) {
    __shared__ float Wl[DIM * DIM];
    for (int i = threadIdx.x; i < DIM * DIM; i += 256) Wl[i] = W[i];
    __syncthreads();
    int r = blockIdx.x * 256 + threadIdx.x;
    if (r >= N) return;
    const float4* xr4 = (const float4*)(x + (size_t)r * DIM);
    float4 acc[16];
#pragma unroll
    for (int j = 0; j < 16; ++j) acc[j] = make_float4(0.f, 0.f, 0.f, 0.f);
    for (int k0 = 0; k0 < 16; ++k0) {
        float4 xv = xr4[k0];
#pragma unroll
        for (int kk = 0; kk < 4; ++kk) {
            float xs = (&xv.x)[kk];
            const float4* wrow = (const float4*)(Wl + (k0 * 4 + kk) * DIM);
#pragma unroll
            for (int j = 0; j < 16; ++j) {
                float4 w = wrow[j];
                acc[j].x += xs * w.x;
                acc[j].y += xs * w.y;
                acc[j].z += xs * w.z;
                acc[j].w += xs * w.w;
            }
        }
    }
    float dr = dinv[r];
    float4* hr4 = (float4*)(h2 + (size_t)r * DIM);
    float4* os4 = (float4*)(outseed + (size_t)r * DIM);
    union { __half2 h[4]; float4 f4; } pack;
#pragma unroll
    for (int j = 0; j < 16; j += 2) {
        float4 v0 = make_float4(acc[j].x * dr, acc[j].y * dr, acc[j].z * dr, acc[j].w * dr);
        float4 v1 = make_float4(acc[j + 1].x * dr, acc[j + 1].y * dr, acc[j + 1].z * dr, acc[j + 1].w * dr);
        os4[j] = v0;
        os4[j + 1] = v1;
        pack.h[0] = __float22half2_rn(make_float2(v0.x, v0.y));
        pack.h[1] = __float22half2_rn(make_float2(v0.z, v0.w));
        pack.h[2] = __float22half2_rn(make_float2(v1.x, v1.y));
        pack.h[3] = __float22half2_rn(make_float2(v1.z, v1.w));
        hr4[j >> 1] = pack.f4;
    }
}

// ---------------- edge-parallel aggregate over sorted edge sources ----------------
__global__ __launch_bounds__(256) void k_edgeagg(
        const int* __restrict__ ssrc, const int* __restrict__ rowptr,
        const int* __restrict__ chunkstart, const __half* __restrict__ h2,
        float* __restrict__ agg, int N, int E) {
    const int lane = threadIdx.x & 63;
    const int wid = blockIdx.x * (blockDim.x >> 6) + (threadIdx.x >> 6);
    const int base = wid << 6;
    if (base >= E) return;
    const int nval = min(64, E - base);
    const int node0 = chunkstart[wid];
    int sv = ssrc[base + min(lane, nval - 1)];
    int nn = node0 + 1 + lane;
    if (nn > N) nn = N;
    int rp = rowptr[nn];  // lane l holds rowptr[node0+1+l]
    const __half* hb = h2 + lane;
    float acc = 0.f;
    bool uncovered = (__builtin_amdgcn_readlane(rp, 63) <= base + nval - 1);
    if (!uncovered && nval == 64) {
        int dprev = node0 + __popcll(__ballot(rp <= base));
#pragma unroll
        for (int g = 0; g < 64; g += 8) {
            int sA[8];
            float vA[8];
            int dA[8];
#pragma unroll
            for (int k = 0; k < 8; ++k) sA[k] = __builtin_amdgcn_readlane(sv, g + k);
#pragma unroll
            for (int k = 0; k < 8; ++k) vA[k] = __half2float(hb[(size_t)sA[k] * DIM]);
#pragma unroll
            for (int k = 0; k < 8; ++k) dA[k] = node0 + __popcll(__ballot(rp <= base + g + k));
#pragma unroll
            for (int k = 0; k < 8; ++k) {
                if (dA[k] != dprev) {  // wave-uniform
                    atomicAdd(&agg[(size_t)dprev * DIM + lane], acc);
                    acc = 0.f;
                    dprev = dA[k];
                }
                acc += vA[k];
            }
        }
        atomicAdd(&agg[(size_t)dprev * DIM + lane], acc);
    } else if (!uncovered) {
        int dprev = node0 + __popcll(__ballot(rp <= base));
        for (int j = 0; j < nval; ++j) {
            int sj = __builtin_amdgcn_readlane(sv, j);
            int dj = node0 + __popcll(__ballot(rp <= base + j));
            if (dj != dprev) {
                atomicAdd(&agg[(size_t)dprev * DIM + lane], acc);
                acc = 0.f;
                dprev = dj;
            }
            acc += __half2float(hb[(size_t)sj * DIM]);
        }
        atomicAdd(&agg[(size_t)dprev * DIM + lane], acc);
    } else {
        // slow path: per-edge binary search (chunk spans >64 nodes; ~never)
        int dprev = -1;
        for (int j = 0; j < nval; ++j) {
            int e = base + j;
            int lo = 0, hi = N - 1;
            while (lo < hi) {
                int mid = (lo + hi + 1) >> 1;
                if (rowptr[mid] <= e) lo = mid; else hi = mid - 1;
            }
            if (lo != dprev) {
                if (dprev >= 0) atomicAdd(&agg[(size_t)dprev * DIM + lane], acc);
                acc = 0.f;
                dprev = lo;
            }
            acc += __half2float(hb[(size_t)__builtin_amdgcn_readlane(sv, j) * DIM]);
        }
        if (dprev >= 0) atomicAdd(&agg[(size_t)dprev * DIM + lane], acc);
    }
}

// ---------------- post: a = relu(out*dinv + b), stats (out pre-seeded w/ self) ----------------
__global__ __launch_bounds__(256) void k_post(
        const float* __restrict__ dinv, const float* __restrict__ b,
        float* __restrict__ out, float* __restrict__ gsum,
        float* __restrict__ gsumsq, int N) {
    __shared__ float s1[256], s2[256];
    const int lane = threadIdx.x & 63;
    const int wave = threadIdx.x >> 6;
    const float bf = b[lane];
    float lsum = 0.f, lsq = 0.f;
    for (int d = blockIdx.x * 4 + wave; d < N; d += gridDim.x * 4) {
        size_t di = (size_t)d * DIM + lane;
        float a = out[di] * dinv[d] + bf;
        a = fmaxf(a, 0.f);
        out[di] = a;
        lsum += a;
        lsq += a * a;
    }
    s1[threadIdx.x] = lsum;
    s2[threadIdx.x] = lsq;
    __syncthreads();
    if (threadIdx.x < 64) {
        float t1 = s1[threadIdx.x] + s1[threadIdx.x + 64] + s1[threadIdx.x + 128] + s1[threadIdx.x + 192];
        float t2 = s2[threadIdx.x] + s2[threadIdx.x + 64] + s2[threadIdx.x + 128] + s2[threadIdx.x + 192];
        atomicAdd(&gsum[threadIdx.x], t1);
        atomicAdd(&gsumsq[threadIdx.x], t2);
    }
}

// ---------------- bn2 (stats fused): out = a*scale + shift, float4, in-place ----------------
__global__ void k_bn2(float4* __restrict__ a, const float* __restrict__ gsum,
                      const float* __restrict__ gsumsq, const float* __restrict__ gamma,
                      const float* __restrict__ beta, int N, int total4) {
    __shared__ float sc[DIM], sh[DIM];
    if (threadIdx.x < DIM) {
        float inv_n = 1.0f / (float)N;
        float mean = gsum[threadIdx.x] * inv_n;
        float var = gsumsq[threadIdx.x] * inv_n - mean * mean;
        float istd = rsqrtf(var + BN_EPS);
        float s = gamma[threadIdx.x] * istd;
        sc[threadIdx.x] = s;
        sh[threadIdx.x] = beta[threadIdx.x] - mean * s;
    }
    __syncthreads();
    int i = blockIdx.x * blockDim.x + threadIdx.x;
    int stride = gridDim.x * blockDim.x;  // 524288 ≡ 0 (mod 16)
    int f4 = i & 15;
    float4 scv = ((const float4*)sc)[f4];
    float4 shv = ((const float4*)sh)[f4];
    for (; i < total4; i += stride) {
        float4 v = a[i];
        v.x = v.x * scv.x + shv.x;
        v.y = v.y * scv.y + shv.y;
        v.z = v.z * scv.z + shv.z;
        v.w = v.w * scv.w + shv.w;
        a[i] = v;
    }
}

extern "C" void kernel_launch(void* const* d_in, const int* in_sizes, int n_in,
                              void* d_out, int out_size, void* d_ws, size_t ws_size,
                              hipStream_t stream) {
    const float* x     = (const float*)d_in[0];
    const int*   ei    = (const int*)d_in[1];
    const float* W     = (const float*)d_in[2];
    const float* b     = (const float*)d_in[3];
    const float* gamma = (const float*)d_in[4];
    const float* beta  = (const float*)d_in[5];
    float* out = (float*)d_out;

    const int N = in_sizes[0] / DIM;  // 100000
    const int E = in_sizes[1] / 2;    // 1000000
    const int* esrc = ei;
    const int* edst = ei + E;
    const int P = (N + RSIZE - 1) >> RSHIFT;   // 391 ranges (<= 512)
    const int nbin = (E + EPB - 1) / EPB;      // 123 bin blocks
    const int nchunks = (E + 63) / 64;         // 15625

    // workspace layout
    char* ws = (char*)d_ws;
    size_t off = 0;
    int* deg = (int*)(ws + off);        off += (size_t)N * sizeof(int);
    off = (off + 255) & ~(size_t)255;
    float* dinv = (float*)(ws + off);   off += (size_t)N * sizeof(float);
    off = (off + 255) & ~(size_t)255;
    int* rowptr = (int*)(ws + off);     off += (size_t)(N + 1) * sizeof(int);
    off = (off + 255) & ~(size_t)255;
    int* rangecnt = (int*)(ws + off);   off += 512 * sizeof(int);
    int* gbase = (int*)(ws + off);      off += 520 * sizeof(int);
    int* gcursor = (int*)(ws + off);    off += 512 * sizeof(int);
    float* gsum = (float*)(ws + off);   off += 64 * sizeof(float);
    float* gsumsq = (float*)(ws + off); off += 64 * sizeof(float);
    off = (off + 255) & ~(size_t)255;
    int* chunkstart = (int*)(ws + off); off += (size_t)nchunks * sizeof(int);
    off = (off + 255) & ~(size_t)255;
    int* pk = (int*)(ws + off);         off += (size_t)E * sizeof(int);
    off = (off + 255) & ~(size_t)255;
    int* ssrc = (int*)(ws + off);       off += (size_t)E * sizeof(int);
    off = (off + 255) & ~(size_t)255;
    __half* h2 = (__half*)(ws + off);   off += (size_t)N * DIM * sizeof(__half);

    hipMemsetAsync(deg, 0, (size_t)N * sizeof(int), stream);

    k_degree<<<((E >> 2) + 255) / 256, 256, 0, stream>>>(edst, deg, E);
    k_prep<<<P, 256, 0, stream>>>(deg, dinv, rangecnt, gsum, N);
    k_rangescan<<<1, 512, 0, stream>>>(rangecnt, gbase, gcursor, rowptr, P, N, E);
    k_bin<<<nbin, 256, 0, stream>>>(esrc, edst, gcursor, pk, P, E);
    k_gemm<<<P, 256, 0, stream>>>(x, W, dinv, h2, out, N);
    k_sortrange<<<P, 256, 0, stream>>>(deg, gbase, pk, ssrc, rowptr, chunkstart, N);
    k_edgeagg<<<(nchunks + 3) / 4, 256, 0, stream>>>(ssrc, rowptr, chunkstart, h2, out, N, E);
    k_post<<<1024, 256, 0, stream>>>(dinv, b, out, gsum, gsumsq, N);
    k_bn2<<<2048, 256, 0, stream>>>((float4*)out, gsum, gsumsq, gamma, beta, N, N * DIM / 4);
}